// Round 7
// baseline (17.108 us; speedup 1.0000x reference)
//
#include <hip/hip_runtime.h>

#define FF 4096      // faces
#define IC 16        // i-chunk per block (staged in LDS)
#define JR 2         // j-faces per thread (register-blocked)
#define BJT 256      // threads per block
#define BJ (BJT * JR)          // 512 j per block
#define NBX (FF / BJ)          // 8
#define NBY (FF / IC)          // 256
#define NPART (NBX * NBY)      // 2048 partials

// ---------------------------------------------------------------------------
// K1: fused pair kernel, JR=2 register-blocked.
// Each thread owns j0 = bx*512+tid and j1 = j0+256 (vertices + centroids in
// registers). Threads 0..15 build the block's i-chunk records (normal,
// ref_dot, centroid, prob) in LDS. Each broadcast i-record read amortizes
// over 2 pair tests -> LDS pressure halved; loop is VALU-bound.
// grid (8,256) = 2048 blocks = 8 blocks/CU = 32 waves/CU.
// Diagonal i==j skipped-test is safe (R6: absmax 0.0).
// ---------------------------------------------------------------------------
__global__ __launch_bounds__(256, 8) void tcl_pairs(
    const float* __restrict__ verts,    // [V,3] f32
    const int* __restrict__ faces,      // [F,3] i32
    const float* __restrict__ probs,    // [F]   f32
    float* __restrict__ partial)
{
    __shared__ float4 s_n[IC];          // (nx,ny,nz,ref_dot)
    __shared__ float4 s_cp[IC];         // (cx,cy,cz,prob)
    __shared__ float s_red[4];

    const int tid = threadIdx.x;
    const int jbase = blockIdx.x * BJ + tid;    // j's: jbase, jbase+256
    const int ibase = blockIdx.y * IC;

    // ---- own j-faces (registers) ----
    float ax[JR], ay[JR], az[JR];
    float bx_[JR], by_[JR], bz_[JR];
    float cx_[JR], cy_[JR], cz_[JR];
    float ex[JR], ey[JR], ez[JR];       // centroids
    #pragma unroll
    for (int k = 0; k < JR; ++k) {
        int j = jbase + k * BJT;
        int a = faces[3 * j + 0];
        int b = faces[3 * j + 1];
        int c = faces[3 * j + 2];
        ax[k] = verts[3 * a]; ay[k] = verts[3 * a + 1]; az[k] = verts[3 * a + 2];
        bx_[k] = verts[3 * b]; by_[k] = verts[3 * b + 1]; bz_[k] = verts[3 * b + 2];
        cx_[k] = verts[3 * c]; cy_[k] = verts[3 * c + 1]; cz_[k] = verts[3 * c + 2];
        ex[k] = (ax[k] + bx_[k] + cx_[k]) * (1.0f / 3.0f);
        ey[k] = (ay[k] + by_[k] + cy_[k]) * (1.0f / 3.0f);
        ez[k] = (az[k] + bz_[k] + cz_[k]) * (1.0f / 3.0f);
    }

    // ---- i-chunk records into LDS (threads 0..IC-1) ----
    if (tid < IC) {
        int i = ibase + tid;
        int a = faces[3 * i + 0];
        int b = faces[3 * i + 1];
        int c = faces[3 * i + 2];
        float p0x = verts[3 * a], p0y = verts[3 * a + 1], p0z = verts[3 * a + 2];
        float p1x = verts[3 * b], p1y = verts[3 * b + 1], p1z = verts[3 * b + 2];
        float p2x = verts[3 * c], p2y = verts[3 * c + 1], p2z = verts[3 * c + 2];

        float v1x = p1x - p0x, v1y = p1y - p0y, v1z = p1z - p0z;
        float v2x = p2x - p0x, v2y = p2y - p0y, v2z = p2z - p0z;
        float nx = v1y * v2z - v1z * v2y;
        float ny = v1z * v2x - v1x * v2z;
        float nz = v1x * v2y - v1y * v2x;
        float nrm = sqrtf(nx * nx + ny * ny + nz * nz);
        float inv = 1.0f / fmaxf(nrm, 1e-12f);
        nx *= inv; ny *= inv; nz *= inv;
        float rd = p0x * nx + p0y * ny + p0z * nz;

        s_n[tid] = make_float4(nx, ny, nz, rd);
        s_cp[tid] = make_float4((p0x + p1x + p2x) * (1.0f / 3.0f),
                                (p0y + p1y + p2y) * (1.0f / 3.0f),
                                (p0z + p1z + p2z) * (1.0f / 3.0f),
                                probs[i]);
    }
    __syncthreads();

    // ---- pair loop ----
    float acc = 0.0f;
    #pragma unroll 8
    for (int ii = 0; ii < IC; ++ii) {
        float4 nf = s_n[ii];                 // broadcast (conflict-free)
        float4 cp = s_cp[ii];

        #pragma unroll
        for (int k = 0; k < JR; ++k) {
            float dx = cp.x - ex[k];
            float dy = cp.y - ey[k];
            float dz = cp.z - ez[k];
            // d2 - 1
            float d2m1 = fmaf(dx, dx, fmaf(dy, dy, fmaf(dz, dz, -1.0f)));

            float S0 = fmaf(ax[k], nf.x, fmaf(ay[k], nf.y, fmaf(az[k], nf.z, -nf.w)));
            float S1 = fmaf(bx_[k], nf.x, fmaf(by_[k], nf.y, fmaf(bz_[k], nf.z, -nf.w)));
            float S2 = fmaf(cx_[k], nf.x, fmaf(cy_[k], nf.y, fmaf(cz_[k], nf.z, -nf.w)));

            // intersection <=> mn<0 && mx>0 <=> mn*mx<0 ; AND d2<1:
            // both conditions <=> max(mn*mx, d2-1) < 0
            float mn = fminf(fminf(S0, S1), S2);   // v_min3_f32
            float mx = fmaxf(fmaxf(S0, S1), S2);   // v_max3_f32
            float t = fmaxf(mn * mx, d2m1);

            acc += (t < 0.0f) ? cp.w : 0.0f;       // prob[i]
        }
    }

    // ---- reduce: wave shuffle, cross-wave LDS, one store per block ----
    #pragma unroll
    for (int off = 32; off > 0; off >>= 1)
        acc += __shfl_down(acc, off, 64);

    int wave = tid >> 6;
    int lane = tid & 63;
    if (lane == 0) s_red[wave] = acc;
    __syncthreads();
    if (tid == 0)
        partial[blockIdx.y * NBX + blockIdx.x] =
            (s_red[0] + s_red[1]) + (s_red[2] + s_red[3]);
}

// ---------------------------------------------------------------------------
// K2: final reduce of 2048 partials -> d_out[0]. One block, 512 threads.
// ---------------------------------------------------------------------------
__global__ __launch_bounds__(512) void tcl_reduce(
    const float4* __restrict__ partial4,
    float* __restrict__ d_out)
{
    __shared__ float s_red[8];
    int tid = threadIdx.x;                 // 512 threads, NPART/4 = 512 float4
    float4 v = partial4[tid];
    float s = (v.x + v.y) + (v.z + v.w);

    #pragma unroll
    for (int off = 32; off > 0; off >>= 1)
        s += __shfl_down(s, off, 64);

    int wave = tid >> 6;
    int lane = tid & 63;
    if (lane == 0) s_red[wave] = s;
    __syncthreads();
    if (tid == 0) {
        float t = 0.0f;
        #pragma unroll
        for (int k = 0; k < 8; ++k) t += s_red[k];
        d_out[0] = t * (1.0f / (float)FF);
    }
}

// ---------------------------------------------------------------------------
extern "C" void kernel_launch(void* const* d_in, const int* in_sizes, int n_in,
                              void* d_out, int out_size, void* d_ws, size_t ws_size,
                              hipStream_t stream)
{
    const float* verts = (const float*)d_in[0];   // [2048,3] f32
    const int* faces   = (const int*)d_in[1];     // [4096,3] int32
    const float* probs = (const float*)d_in[2];   // [4096] f32
    float* out = (float*)d_out;
    float* partial = (float*)d_ws;

    dim3 grid(NBX, NBY);                          // (8,256) = 2048 blocks
    tcl_pairs<<<grid, BJT, 0, stream>>>(verts, faces, probs, partial);

    tcl_reduce<<<1, 512, 0, stream>>>((const float4*)partial, out);
}